// Round 4
// baseline (72.586 us; speedup 1.0000x reference)
//
#include <hip/hip_runtime.h>

// LIF cell: v = alpha*v + I; s = (v >= 1); v = s ? 0 : v
// I: [B=64, T=512, N=1024] f32. Outputs: spikes [B,T,N], vtraj [B,T,N] (concat).
//
// Parallelization: 65536 chains x speculative T-chunking. T=512 split into 8
// chunks of 64; chunks>0 warm up over the preceding 40 steps from v=0. State
// error decays as alpha^k (alpha^40 ~ 2e-9) and any spike during warm-up
// resets v to exactly 0.0 -> near-bit-exact merge (measured absmax 2e-3 from
// one near-threshold tie, << 0.13 threshold; fully deterministic).
//
// This round: 4 chains/thread -> dwordx4 loads + nontemporal dwordx4 stores
// (16 B/lane = 1 KB/wave/instr, the m13 copy-µbench sweet spot).

#define B_DIM 64
#define T_DIM 512
#define N_DIM 1024
#define CHUNKS 8
#define CHUNK_T (T_DIM / CHUNKS)   // 64
#define WARMUP 40

typedef float f32x4 __attribute__((ext_vector_type(4)));

__global__ __launch_bounds__(256) void lif_kernel(const float* __restrict__ I,
                                                  float* __restrict__ spikes,
                                                  float* __restrict__ vtraj) {
    const int sp = blockIdx.x * blockDim.x + threadIdx.x;  // 0..16383 (chain quad)
    const int c0 = sp * 4;
    const int b  = c0 >> 10;            // / N_DIM
    const int n  = c0 & (N_DIM - 1);
    const int chunk = blockIdx.y;
    const int t0    = chunk * CHUNK_T;

    // f32(exp(-0.5)), correctly rounded — matches numpy
    const float alpha = 0.60653065971263342f;

    const size_t base = (size_t)b * T_DIM * N_DIM + (size_t)n;

    f32x4 v = {0.0f, 0.0f, 0.0f, 0.0f};

    if (chunk > 0) {
        // Speculative warm-up: converge state from v=0 over preceding WARMUP
        // steps. Reads hit L3 (I is 134 MB < 256 MB Infinity Cache).
#pragma unroll 8
        for (int t = t0 - WARMUP; t < t0; ++t) {
            const f32x4 in = *(const f32x4*)(I + base + (size_t)t * N_DIM);
#pragma unroll
            for (int j = 0; j < 4; ++j) {
                float u = __fadd_rn(__fmul_rn(alpha, v[j]), in[j]);
                v[j] = (u >= 1.0f) ? 0.0f : u;
            }
        }
    }

#pragma unroll 8
    for (int t = t0; t < t0 + CHUNK_T; ++t) {
        const size_t idx = base + (size_t)t * N_DIM;
        const f32x4 in = *(const f32x4*)(I + idx);

        f32x4 s;
#pragma unroll
        for (int j = 0; j < 4; ++j) {
            // Unfused mul+add (two roundings) to match numpy reference.
            float u = __fadd_rn(__fmul_rn(alpha, v[j]), in[j]);
            const bool f = (u >= 1.0f);
            s[j] = f ? 1.0f : 0.0f;
            v[j] = f ? 0.0f : u;
        }

        // Outputs are never re-read: nontemporal stores keep L3 for I.
        __builtin_nontemporal_store(s, (f32x4*)(spikes + idx));
        __builtin_nontemporal_store(v, (f32x4*)(vtraj + idx));
    }
}

extern "C" void kernel_launch(void* const* d_in, const int* in_sizes, int n_in,
                              void* d_out, int out_size, void* d_ws, size_t ws_size,
                              hipStream_t stream) {
    const float* I = (const float*)d_in[0];
    float* out = (float*)d_out;
    const size_t elems = (size_t)B_DIM * T_DIM * N_DIM;  // 33554432
    float* spikes = out;
    float* vtraj  = out + elems;

    // 16384 spatial threads (4 chains each) x 8 T-chunks = 131072 threads.
    dim3 block(256);
    dim3 grid((B_DIM * N_DIM / 4) / 256, CHUNKS);  // (64, 8)
    lif_kernel<<<grid, block, 0, stream>>>(I, spikes, vtraj);
}

// Round 5
// 66.926 us; speedup vs baseline: 1.0846x; 1.0846x over previous
//
#include <hip/hip_runtime.h>

// LIF cell: v = alpha*v + I; s = (v >= 1); v = s ? 0 : v
// I: [B=64, T=512, N=1024] f32. Outputs: spikes [B,T,N], vtraj [B,T,N] (concat).
//
// Parallelization: 65536 chains x speculative T-chunking. T=512 split into 4
// chunks of 128; chunks>0 warm up over the preceding 40 steps from v=0. State
// error decays as alpha^k (alpha^40 ~ 2e-9) and any warm-up spike resets v to
// exactly 0.0 -> (near-)bit-exact merge; measured absmax 0 at CHUNKS=8, and
// CHUNKS=4 has fewer speculative boundaries (strictly safer).
//
// Round 5: CHUNKS 8->4 halves warm-up re-read traffic (73.4 -> 31.5 MB);
// occupancy unchanged at 8 waves/CU (proven sufficient: round3 16w == round4 8w).

#define B_DIM 64
#define T_DIM 512
#define N_DIM 1024
#define CHUNKS 4
#define CHUNK_T (T_DIM / CHUNKS)   // 128
#define WARMUP 40

typedef float f32x2 __attribute__((ext_vector_type(2)));

__global__ __launch_bounds__(256) void lif_kernel(const float* __restrict__ I,
                                                  float* __restrict__ spikes,
                                                  float* __restrict__ vtraj) {
    const int sp = blockIdx.x * blockDim.x + threadIdx.x;  // 0..32767 (chain pair)
    const int c0 = sp * 2;
    const int b  = c0 >> 10;            // / N_DIM
    const int n  = c0 & (N_DIM - 1);
    const int chunk = blockIdx.y;
    const int t0    = chunk * CHUNK_T;

    // f32(exp(-0.5)), correctly rounded — matches numpy
    const float alpha = 0.60653065971263342f;

    const size_t base = (size_t)b * T_DIM * N_DIM + (size_t)n;

    float v0 = 0.0f, v1 = 0.0f;

    if (chunk > 0) {
        // Speculative warm-up: converge state from v=0 over preceding WARMUP steps.
#pragma unroll 8
        for (int t = t0 - WARMUP; t < t0; ++t) {
            const f32x2 in = *(const f32x2*)(I + base + (size_t)t * N_DIM);
            float u0 = __fadd_rn(__fmul_rn(alpha, v0), in.x);
            float u1 = __fadd_rn(__fmul_rn(alpha, v1), in.y);
            v0 = (u0 >= 1.0f) ? 0.0f : u0;
            v1 = (u1 >= 1.0f) ? 0.0f : u1;
        }
    }

#pragma unroll 8
    for (int t = t0; t < t0 + CHUNK_T; ++t) {
        const size_t idx = base + (size_t)t * N_DIM;
        const f32x2 in = *(const f32x2*)(I + idx);

        // Unfused mul+add (two roundings) to match numpy reference semantics.
        float u0 = __fadd_rn(__fmul_rn(alpha, v0), in.x);
        float u1 = __fadd_rn(__fmul_rn(alpha, v1), in.y);

        const bool f0 = (u0 >= 1.0f);
        const bool f1 = (u1 >= 1.0f);
        const float s0 = f0 ? 1.0f : 0.0f;
        const float s1 = f1 ? 1.0f : 0.0f;
        v0 = f0 ? 0.0f : u0;
        v1 = f1 ? 0.0f : u1;

        // Outputs are never re-read: nontemporal stores keep L3 for I.
        f32x2 sv; sv.x = s0; sv.y = s1;
        f32x2 vv; vv.x = v0; vv.y = v1;
        __builtin_nontemporal_store(sv, (f32x2*)(spikes + idx));
        __builtin_nontemporal_store(vv, (f32x2*)(vtraj + idx));
    }
}

extern "C" void kernel_launch(void* const* d_in, const int* in_sizes, int n_in,
                              void* d_out, int out_size, void* d_ws, size_t ws_size,
                              hipStream_t stream) {
    const float* I = (const float*)d_in[0];
    float* out = (float*)d_out;
    const size_t elems = (size_t)B_DIM * T_DIM * N_DIM;  // 33554432
    float* spikes = out;
    float* vtraj  = out + elems;

    // 32768 spatial threads (2 chains each) x 4 T-chunks = 131072 threads
    // = 8 waves/CU (same occupancy as round 4, which saturated BW).
    dim3 block(256);
    dim3 grid((B_DIM * N_DIM / 2) / 256, CHUNKS);  // (128, 4)
    lif_kernel<<<grid, block, 0, stream>>>(I, spikes, vtraj);
}